// Round 11
// baseline (381.669 us; speedup 1.0000x reference)
//
#include <hip/hip_runtime.h>
#include <math.h>

#define NB 64
#define NN 207
#define NT 48
#define NF 6
#define NH 64
#define NSEQ (NB*NN)        // 13248 = 414*32
#define NG2  (NSEQ/32)      // 414 LSTM blocks of 32 seqs
#define TSU  ((size_t)NSEQ*NH)   // ELEMENTS per t-plane of sxp (uint each: hi<<16|lo)

typedef short bf8_t __attribute__((ext_vector_type(8)));
typedef float f4_t  __attribute__((ext_vector_type(4)));
typedef unsigned short ushort;
typedef unsigned int uint;

__device__ __forceinline__ ushort bf16h(float x){
  uint u = __float_as_uint(x);
  return (ushort)((u + 0x7FFF + ((u>>16)&1)) >> 16);
}
__device__ __forceinline__ float bf16f(ushort h){
  return __uint_as_float((uint)h << 16);
}
__device__ __forceinline__ float fsig(float x){
  return __builtin_amdgcn_rcpf(1.0f + __expf(-x));
}
__device__ __forceinline__ float ftanh(float x){
  x = fminf(15.0f, fmaxf(-15.0f, x));
  float e = __expf(2.0f*x);
  return 1.0f - 2.0f*__builtin_amdgcn_rcpf(e + 1.0f);
}

// raw workgroup barrier that orders LDS ONLY — no vmcnt drain, so global
// loads/stores stay in flight across it (T4: counted waits, never drain-0).
__device__ __forceinline__ void lds_barrier(){
  __builtin_amdgcn_sched_barrier(0);
  asm volatile("s_waitcnt lgkmcnt(0)" ::: "memory");
  __builtin_amdgcn_s_barrier();
  __builtin_amdgcn_s_barrier();  // no-op duplicate guard removed below if miscompiles
}

// NOTE: the duplicate s_barrier above would be wrong — define properly:
#undef  GCN_DUMMY
__device__ __forceinline__ void lds_barrier2(){
  __builtin_amdgcn_sched_barrier(0);
  asm volatile("s_waitcnt lgkmcnt(0)" ::: "memory");
  __builtin_amdgcn_s_barrier();
  __builtin_amdgcn_sched_barrier(0);
}

// interchange: sxp[t][seq][64] uint, each = (bf16hi<<16)|bf16lo of GCN output.

// ---------------- GCN v11: ONE t-plane per block (3072 blocks) ----------------
// r10 post-mortem: 3 consecutive intra-phase micro-fixes were no-ops; the
// surviving hypothesis is the in-block convoy (6 serial tt x 2 barriers with
// only 2 blocks/CU to fill drains). v11 deletes the serial chain: each block
// does exactly one t-plane (prologue -> L1 -> BAR -> S2+MFMA -> BAR ->
// epilogue -> exit). Block turnover is barrier-free, so the CU overlaps one
// block's epilogue/store-drain with the next block's prologue/L1. Bonus: xs
// stride 40->10 floats fixes a latent 4-way same-bank conflict (n-delta 4 *
// 40 words == bank 0). Arithmetic and summation grouping unchanged.
#define HW 72
#define XS10 10
#define GCN1T_LDS_BYTES (208*HW*2 + (207*XS10 + NF*64 + 64 + 64 + 64 + 64 + 8)*4)

__global__ __launch_bounds__(256, 2) void gcn_kernel(
    const float* __restrict__ x, const float* __restrict__ W1, const float* __restrict__ b1,
    const float* __restrict__ W2, const float* __restrict__ b2,
    uint* __restrict__ sxp)
{
  extern __shared__ char smraw[];
  ushort* h1b = (ushort*)smraw;            // [208][72] bf16 (row 207 = zero pad)
  float*  xs  = (float*)(h1b + 208*HW);    // [207][10] (stride 10: bank-clean, float2-aligned)
  float*  W1s = xs + 207*XS10;             // [6][64]
  float*  b1s = W1s + NF*64;
  float*  b2s = b1s + 64;
  float*  S2_ = b2s + 64;                  // [64]
  float*  r1_ = S2_ + 64;                  // [64]
  float*  xsA = r1_ + 64;                  // [8]

  const int tid = threadIdx.x;
  const int t = blockIdx.x, b = blockIdx.y;
  const float inv = 1.0f/208.0f;
  const int l = tid & 63;
  const int w = __builtin_amdgcn_readfirstlane(tid >> 6);
  const int col = l & 15, q = l >> 4;
  const int cw = w*16 + col;

  if (tid < 64){ S2_[tid]=0.f; r1_[tid]=0.f; }
  if (tid < 8) xsA[tid] = 0.f;
  if (tid < 72) h1b[207*HW + tid] = 0;

  for (int i=tid;i<NF*64;i+=256) W1s[i]=W1[i];
  if (tid<64){ b1s[tid]=b1[tid]; b2s[tid]=b2[tid]; }
  // x staging: thread n<207 loads x[b][n][t][0..5] (24B, 8B-aligned) as 3 float2
  if (tid < NN){
    const float* xb = x + ((size_t)(b*NN + tid)*NT + t)*NF;
    float2 v0 = *(const float2*)(xb);
    float2 v1 = *(const float2*)(xb+2);
    float2 v2 = *(const float2*)(xb+4);
    *(float2*)&xs[tid*XS10+0] = v0;
    *(float2*)&xs[tid*XS10+2] = v1;
    *(float2*)&xs[tid*XS10+4] = v2;
  }
  __syncthreads();

  // feature sums over n (4 partials per f, same grouping as before)
  if (tid < 24){
    int f = tid>>2, p = tid&3;
    float ps = 0.f;
    for (int n=p; n<NN; n+=4) ps += xs[n*XS10 + f];
    atomicAdd(&xsA[f], ps);
  }

  // W2 frags (layer-2 B operand, single-bf16) + S2 W2-slice in regs
  float wtmp[16];
  #pragma unroll
  for (int kc=0;kc<2;kc++)
    #pragma unroll
    for (int j=0;j<8;j++)
      wtmp[kc*8+j] = W2[(size_t)(kc*32 + q*8 + j)*64 + cw];
  bf8_t B2[2];
  #pragma unroll
  for (int kc=0;kc<2;kc++){
    bf8_t ph;
    #pragma unroll
    for (int j=0;j<8;j++) ph[j] = (short)bf16h(wtmp[kc*8+j]);
    B2[kc]=ph;
  }
  const int h2i = tid & 63, pp2 = tid >> 6;
  float w2c[16];
  #pragma unroll
  for (int k=0;k<16;k++) w2c[k] = W2[(size_t)(pp2*16+k)*64 + h2i];

  __syncthreads();

  const int ht4 = (tid & 15) * 4;
  const int nti = tid >> 4;

  // ---- layer 1: h1 = relu((x@W1 + S1)/208 + b1) -> bf16 plane + r1 ----
  {
    float s1v[4];
    #pragma unroll
    for (int j=0;j<4;j++){
      float a = 0.f;
      #pragma unroll
      for (int f=0;f<NF;f++) a += xsA[f]*W1s[f*64 + ht4 + j];
      s1v[j] = a;
    }
    float cs0=0.f, cs1=0.f, cs2=0.f, cs3=0.f;
    #pragma unroll 1
    for (int p=0;p<4;p++){
      int nt = p*16 + nti;
      if (nt < 52){
        #pragma unroll
        for (int i=0;i<4;i++){
          int n = 4*nt+i;
          if (n < NN){
            float a0=0.f,a1=0.f,a2=0.f,a3=0.f;
            #pragma unroll
            for (int f=0;f<NF;f++){
              float xv = xs[n*XS10 + f];
              float4 wv = *(const float4*)&W1s[f*64 + ht4];
              a0+=xv*wv.x; a1+=xv*wv.y; a2+=xv*wv.z; a3+=xv*wv.w;
            }
            float v0=(a0+s1v[0])*inv + b1s[ht4+0]; v0 = v0>0.f?v0:0.f;
            float v1=(a1+s1v[1])*inv + b1s[ht4+1]; v1 = v1>0.f?v1:0.f;
            float v2=(a2+s1v[2])*inv + b1s[ht4+2]; v2 = v2>0.f?v2:0.f;
            float v3=(a3+s1v[3])*inv + b1s[ht4+3]; v3 = v3>0.f?v3:0.f;
            ushort4 hi;
            hi.x=bf16h(v0); hi.y=bf16h(v1); hi.z=bf16h(v2); hi.w=bf16h(v3);
            *(ushort4*)&h1b[n*HW + ht4] = hi;
            cs0+=v0; cs1+=v1; cs2+=v2; cs3+=v3;
          }
        }
      }
    }
    atomicAdd(&r1_[ht4+0], cs0);
    atomicAdd(&r1_[ht4+1], cs1);
    atomicAdd(&r1_[ht4+2], cs2);
    atomicAdd(&r1_[ht4+3], cs3);
  }
  lds_barrier2();   // h1b writes + r1 atomics visible

  // ---- S2 = r1 @ W2 (fp32 exact, W2 slice from regs) ----
  {
    float ps = 0.f;
    #pragma unroll
    for (int k=0;k<16;k++) ps += r1_[pp2*16+k]*w2c[k];
    atomicAdd(&S2_[h2i], ps);
  }

  // ---- layer 2: single-bf16 MFMA ----
  f4_t acc[13];
  #pragma unroll
  for (int mt=0;mt<13;mt++){ f4_t z; z[0]=0.f;z[1]=0.f;z[2]=0.f;z[3]=0.f; acc[mt]=z; }
  #pragma unroll 2
  for (int mt=0;mt<13;mt++){
    #pragma unroll
    for (int kc=0;kc<2;kc++){
      bf8_t ah = *(const bf8_t*)(h1b + (mt*16+col)*HW + kc*32 + q*8);
      acc[mt] = __builtin_amdgcn_mfma_f32_16x16x32_bf16(ah, B2[kc], acc[mt], 0,0,0);
    }
  }
  lds_barrier2();   // S2 atomics complete; h1b reads done (block exits after)

  // ---- epilogue: h2 split-bf16 -> packed dword at [t][b*207+n][cw] ----
  {
    const float s2v = S2_[cw], b2v = b2s[cw];
    const size_t obase = (size_t)t*TSU + (size_t)(b*NN)*NH + cw;
    #pragma unroll
    for (int mt=0;mt<13;mt++){
      #pragma unroll
      for (int r=0;r<4;r++){
        int n = mt*16 + q*4 + r;
        if (n < NN){
          float v = (acc[mt][r] + s2v)*inv + b2v;
          v = v>0.f ? v : 0.f;
          ushort hb = bf16h(v);
          ushort lb = bf16h(v - bf16f(hb));
          sxp[obase + (size_t)n*NH] = ((uint)hb << 16) | (uint)lb;
        }
      }
    }
  }
}

// ---------------- LSTM v21 (best measured: 166 us) — unchanged ----------------
#define HS2 72   // ushort stride per h row

__global__ __launch_bounds__(256, 2) void lstm21_kernel(
    const uint* __restrict__ sxp,
    const float* __restrict__ Wih, const float* __restrict__ Whh,
    const float* __restrict__ bih, const float* __restrict__ bhh,
    const float* __restrict__ Wfc, const float* __restrict__ bfc, float* __restrict__ out)
{
  __shared__ __align__(16) ushort hhp[2][2][16*HS2 + 8];   // [buf][set] hi plane (9.3 KB)
  __shared__ __align__(16) ushort hlp[2][2][16*HS2 + 8];   // [buf][set] lo plane (9.3 KB)
  __shared__ __align__(16) ushort xst[2][2][2][2][512];    // [par][set][plane][kk][512] (16 KB)

  const int tid = threadIdx.x;
  const int l = tid & 63;
  const int w = __builtin_amdgcn_readfirstlane(tid >> 6);
  const int col = l & 15, q = l >> 4;
  const int g = blockIdx.x;

  // B fragments: [ty][mat*2+kk]; mat 0 = Wih (x), 1 = Whh (h). 128 VGPRs.
  bf8_t Bh[4][4], Bl[4][4];
  #pragma unroll
  for (int mat=0; mat<2; mat++){
    const float* W = mat ? Whh : Wih;
    #pragma unroll
    for (int ty=0; ty<4; ty++){
      #pragma unroll
      for (int kk=0; kk<2; kk++){
        const float* wp = W + (size_t)(ty*64 + w*16 + col)*64 + kk*32 + q*8;
        bf8_t ph, pl2;
        #pragma unroll
        for (int j=0;j<8;j++){
          float wv = wp[j];
          ushort hb = bf16h(wv);
          ph[j] = (short)hb;
          pl2[j] = (short)bf16h(wv - bf16f(hb));
        }
        Bh[ty][mat*2+kk] = ph;
        Bl[ty][mat*2+kk] = pl2;
      }
    }
  }
  float bias[4];
  #pragma unroll
  for (int ty=0;ty<4;ty++){
    int r = ty*64 + w*16 + col;
    bias[ty] = bih[r] + bhh[r];
  }
  float c[2][4];
  #pragma unroll
  for (int s=0;s<2;s++)
    #pragma unroll
    for (int i=0;i<4;i++) c[s][i]=0.f;

  for (int i=tid; i<16*HS2; i+=256){
    hhp[0][0][i]=0; hhp[0][1][i]=0; hlp[0][0][i]=0; hlp[0][1][i]=0;
  }

  // stage role: wave w owns (set ss, k-half hf); lane loads 8 packed dwords
  // = h-dims hf*32+q*8 .. +8 of seq (g*32 + ss*16 + col).
  const int ss = w >> 1, hf = w & 1;
  const uint* xsrc = sxp + (size_t)(g*32 + ss*16 + col)*64 + (size_t)(hf*32 + q*8);

  // de-interleave 8 packed dwords -> hi uint4 + lo uint4 (2 ushorts each)
  #define DEINT(A8, B8, HU, LU) do { \
    uint _d[8] = {(A8).x,(A8).y,(A8).z,(A8).w,(B8).x,(B8).y,(B8).z,(B8).w}; \
    (HU).x = (_d[1] & 0xffff0000u) | (_d[0] >> 16); \
    (HU).y = (_d[3] & 0xffff0000u) | (_d[2] >> 16); \
    (HU).z = (_d[5] & 0xffff0000u) | (_d[4] >> 16); \
    (HU).w = (_d[7] & 0xffff0000u) | (_d[6] >> 16); \
    (LU).x = (_d[1] << 16) | (_d[0] & 0xffffu); \
    (LU).y = (_d[3] << 16) | (_d[2] & 0xffffu); \
    (LU).z = (_d[5] << 16) | (_d[4] & 0xffffu); \
    (LU).w = (_d[7] << 16) | (_d[6] & 0xffffu); \
  } while(0)

  // prologue: stage t=0 -> xst[0], t=1 -> xst[1]
  #pragma unroll
  for (int t2=0; t2<2; t2++){
    uint4 a8 = *(const uint4*)(xsrc + (size_t)t2*TSU);
    uint4 b8 = *(const uint4*)(xsrc + (size_t)t2*TSU + 4);
    uint4 hu, lu;
    DEINT(a8, b8, hu, lu);
    *(uint4*)&xst[t2][ss][0][hf][l*8] = hu;
    *(uint4*)&xst[t2][ss][1][hf][l*8] = lu;
  }

  const int d = w*16 + col;
  __syncthreads();

  #pragma unroll 2
  for (int t=0; t<NT; t++){
    const int cur = t & 1;

    // ---- stage issue for t+2 (regs; LDS-written post-barrier) ----
    uint4 ga, gb;
    const bool do_stage = (t+2 < NT);
    if (do_stage){
      ga = *(const uint4*)(xsrc + (size_t)(t+2)*TSU);
      gb = *(const uint4*)(xsrc + (size_t)(t+2)*TSU + 4);
    }

    // ---- x-phase: lane-linear frag reads (conflict-free), 48 MFMAs ----
    bf8_t xh0[2], xh1[2], xl0[2], xl1[2];
    #pragma unroll
    for (int s=0;s<2;s++){
      xh0[s] = *(const bf8_t*)&xst[cur][s][0][0][l*8];
      xh1[s] = *(const bf8_t*)&xst[cur][s][0][1][l*8];
      xl0[s] = *(const bf8_t*)&xst[cur][s][1][0][l*8];
      xl1[s] = *(const bf8_t*)&xst[cur][s][1][1][l*8];
    }

    f4_t acc[2][4];
    #pragma unroll
    for (int s=0;s<2;s++)
      #pragma unroll
      for (int ty=0;ty<4;ty++){ f4_t z; z[0]=bias[ty];z[1]=bias[ty];z[2]=bias[ty];z[3]=bias[ty]; acc[s][ty]=z; }
    #pragma unroll
    for (int s=0;s<2;s++)
      #pragma unroll
      for (int ty=0;ty<4;ty++){
        acc[s][ty] = __builtin_amdgcn_mfma_f32_16x16x32_bf16(xh0[s], Bh[ty][0], acc[s][ty], 0,0,0);
        acc[s][ty] = __builtin_amdgcn_mfma_f32_16x16x32_bf16(xl0[s], Bh[ty][0], acc[s][ty], 0,0,0);
        acc[s][ty] = __builtin_amdgcn_mfma_f32_16x16x32_bf16(xh0[s], Bl[ty][0], acc[s][ty], 0,0,0);
        acc[s][ty] = __builtin_amdgcn_mfma_f32_16x16x32_bf16(xh1[s], Bh[ty][1], acc[s][ty], 0,0,0);
        acc[s][ty] = __builtin_amdgcn_mfma_f32_16x16x32_bf16(xl1[s], Bh[ty][1], acc[s][ty], 0,0,0);
        acc[s][ty] = __builtin_amdgcn_mfma_f32_16x16x32_bf16(xh1[s], Bl[ty][1], acc[s][ty], 0,0,0);
      }

    lds_barrier2();   // h(t-1) + xst[cur] reads drained; x prefetch NOT drained

    // ---- h-phase: ds_read_b128 straight into A-frags, 48 MFMAs ----
    bf8_t hh0[2], hh1[2], hl0[2], hl1[2];
    #pragma unroll
    for (int s=0;s<2;s++){
      const ushort* ph = &hhp[cur][s][0] + col*HS2 + q*8;
      const ushort* pl2 = &hlp[cur][s][0] + col*HS2 + q*8;
      hh0[s] = *(const bf8_t*)(ph);
      hh1[s] = *(const bf8_t*)(ph + 32);
      hl0[s] = *(const bf8_t*)(pl2);
      hl1[s] = *(const bf8_t*)(pl2 + 32);
    }
    #pragma unroll
    for (int s=0;s<2;s++)
      #pragma unroll
      for (int ty=0;ty<4;ty++){
        acc[s][ty] = __builtin_amdgcn_mfma_f32_16x16x32_bf16(hh0[s], Bh[ty][2], acc[s][ty], 0,0,0);
        acc[s][ty] = __builtin_amdgcn_mfma_f32_16x16x32_bf16(hl0[s], Bh[ty][2], acc[s][ty], 0,0,0);
        acc[s][ty] = __builtin_amdgcn_mfma_f32_16x16x32_bf16(hh0[s], Bl[ty][2], acc[s][ty], 0,0,0);
        acc[s][ty] = __builtin_amdgcn_mfma_f32_16x16x32_bf16(hh1[s], Bh[ty][3], acc[s][ty], 0,0,0);
        acc[s][ty] = __builtin_amdgcn_mfma_f32_16x16x32_bf16(hl1[s], Bh[ty][3], acc[s][ty], 0,0,0);
        acc[s][ty] = __builtin_amdgcn_mfma_f32_16x16x32_bf16(hh1[s], Bl[ty][3], acc[s][ty], 0,0,0);
      }

    // ---- stage write (t+2) into xst[cur]: post-barrier, so all waves'
    //      reads of this buffer are drained; next barrier publishes it ----
    if (do_stage){
      uint4 hu, lu;
      DEINT(ga, gb, hu, lu);
      *(uint4*)&xst[cur][ss][0][hf][l*8] = hu;
      *(uint4*)&xst[cur][ss][1][hf][l*8] = lu;
    }

    // ---- epilogue both sets: gates -> c,h; cvt_pk split-pack ----
    #pragma unroll
    for (int s=0;s<2;s++){
      ushort* wh = &hhp[cur^1][s][0];
      ushort* wl = &hlp[cur^1][s][0];
      float hv[4];
      #pragma unroll
      for (int r=0;r<4;r++){
        float ig = fsig(acc[s][0][r]);
        float fg = fsig(acc[s][1][r]);
        float gt = ftanh(acc[s][2][r]);
        float og = fsig(acc[s][3][r]);
        float cc = fg*c[s][r] + ig*gt;
        c[s][r] = cc;
        hv[r] = og*ftanh(cc);
      }
      const int o0 = (q*4)*HS2 + d;
      if (t != NT-1){
        uint ph01, ph23, pl01, pl23;
        asm("v_cvt_pk_bf16_f32 %0, %1, %2" : "=v"(ph01) : "v"(hv[0]), "v"(hv[1]));
        asm("v_cvt_pk_bf16_f32 %0, %1, %2" : "=v"(ph23) : "v"(hv[2]), "v"(hv[3]));
        float r0 = hv[0] - __uint_as_float(ph01 << 16);
        float r1 = hv[1] - __uint_as_float(ph01 & 0xffff0000u);
        float r2 = hv[2] - __uint_as_float(ph23 << 16);
        float r3 = hv[3] - __uint_as_float(ph23 & 0xffff0000u);
        asm("v_cvt_pk_bf16_f32 %0, %1, %2" : "=v"(pl01) : "v"(r0), "v"(r1));
        asm("v_cvt_pk_bf16_f32 %0, %1, %2" : "=v"(pl23) : "v"(r2), "v"(r3));
        wh[o0]         = (ushort)ph01;
        wh[o0 + HS2]   = (ushort)(ph01 >> 16);
        wh[o0 + 2*HS2] = (ushort)ph23;
        wh[o0 + 3*HS2] = (ushort)(ph23 >> 16);
        wl[o0]         = (ushort)pl01;
        wl[o0 + HS2]   = (ushort)(pl01 >> 16);
        wl[o0 + 2*HS2] = (ushort)pl23;
        wl[o0 + 3*HS2] = (ushort)(pl23 >> 16);
      } else {
        #pragma unroll
        for (int r=0;r<4;r++){
          uint bits = __float_as_uint(hv[r]);
          wh[o0 + r*HS2] = (ushort)(bits >> 16);
          wl[o0 + r*HS2] = (ushort)(bits & 0xffffu);
        }
      }
    }
  }
  __syncthreads();   // final h (f32 bits split across planes) visible to FC lanes

  if (tid < 32){
    const int s = tid >> 4, r = tid & 15;
    float a = bfc[0];
    const ushort* fh = &hhp[NT&1][s][0] + r*HS2;
    const ushort* fl = &hlp[NT&1][s][0] + r*HS2;
    #pragma unroll 8
    for (int k=0;k<64;k++){
      float v = __uint_as_float(((uint)fh[k] << 16) | (uint)fl[k]);
      a += v * Wfc[k];
    }
    out[g*32 + tid] = a;
  }
}

extern "C" void kernel_launch(void* const* d_in, const int* in_sizes, int n_in,
                              void* d_out, int out_size, void* d_ws, size_t ws_size,
                              hipStream_t stream) {
  const float* x   = (const float*)d_in[0];
  // d_in[1], d_in[2] (N1, N2): structurally dead — sigmoid(N1@N2)>0 is all-ones.
  const float* W1  = (const float*)d_in[3];
  const float* b1  = (const float*)d_in[4];
  const float* W2  = (const float*)d_in[5];
  const float* b2  = (const float*)d_in[6];
  const float* Wih = (const float*)d_in[7];
  const float* Whh = (const float*)d_in[8];
  const float* bih = (const float*)d_in[9];
  const float* bhh = (const float*)d_in[10];
  const float* Wfc = (const float*)d_in[11];
  const float* bfc = (const float*)d_in[12];

  uint* sxp = (uint*)d_ws;                     // [48][13248][64] packed (hi<<16|lo), 162.8 MB
  float* out = (float*)d_out;

  hipFuncSetAttribute((const void*)gcn_kernel, hipFuncAttributeMaxDynamicSharedMemorySize, GCN1T_LDS_BYTES);

  gcn_kernel<<<dim3(NT, NB), 256, GCN1T_LDS_BYTES, stream>>>(x, W1, b1, W2, b2, sxp);
  lstm21_kernel<<<NG2, 256, 0, stream>>>(sxp, Wih, Whh, bih, bhh, Wfc, bfc, out);
}

// Round 12
// 295.462 us; speedup vs baseline: 1.2918x; 1.2918x over previous
//
#include <hip/hip_runtime.h>
#include <math.h>

#define NB 64
#define NN 207
#define NT 48
#define NF 6
#define NH 64
#define NSEQ (NB*NN)        // 13248 = 414*32
#define NG2  (NSEQ/32)      // 414 LSTM blocks of 32 seqs
#define TSU  ((size_t)NSEQ*NH)   // ELEMENTS per t-plane of sxp (uint each: hi<<16|lo)

typedef short bf8_t __attribute__((ext_vector_type(8)));
typedef float f4_t  __attribute__((ext_vector_type(4)));
typedef unsigned short ushort;
typedef unsigned int uint;

__device__ __forceinline__ ushort bf16h(float x){
  uint u = __float_as_uint(x);
  return (ushort)((u + 0x7FFF + ((u>>16)&1)) >> 16);
}
__device__ __forceinline__ float bf16f(ushort h){
  return __uint_as_float((uint)h << 16);
}
__device__ __forceinline__ float fsig(float x){
  return __builtin_amdgcn_rcpf(1.0f + __expf(-x));
}
__device__ __forceinline__ float ftanh(float x){
  x = fminf(15.0f, fmaxf(-15.0f, x));
  float e = __expf(2.0f*x);
  return 1.0f - 2.0f*__builtin_amdgcn_rcpf(e + 1.0f);
}

// raw workgroup barrier that orders LDS ONLY — no vmcnt drain, so global
// loads/stores stay in flight across it (T4: counted waits, never drain-0).
__device__ __forceinline__ void lds_barrier(){
  __builtin_amdgcn_sched_barrier(0);
  asm volatile("s_waitcnt lgkmcnt(0)" ::: "memory");
  __builtin_amdgcn_s_barrier();
  __builtin_amdgcn_sched_barrier(0);
}

// interchange: sxp[t][seq][64] uint, each = (bf16hi<<16)|bf16lo of GCN output.

// ---------------- GCN v12: v10 (6 tt/block, best) + L1 latency fixes ----------------
// r11 decomposition: prologue P~17us, per-plane T~19us (6T dominates). v11's
// 1-plane/block split paid P 6x more often -> reverted to 6 tt/block.
// T fixes: (1) XS6 40->36: xv reads had 4 distinct n with delta 4*40=160
// words == bank 0 (4-way conflict, 1.58x) -> 144 == bank 16 (2-way, free);
// (2) p-loop fully unrolled: 4 independent {6 ds_read + 24 FMA} chains of
// ILP instead of one serial chain (only 2 waves/SIMD to hide latency).
#define HW 72
#define XS6 36
#define GCN7_LDS_BYTES (208*HW*2 + (207*XS6 + NF*64 + 64 + 64 + 6*64 + 6*64 + 48)*4)

__global__ __launch_bounds__(256, 2) void gcn_kernel(
    const float* __restrict__ x, const float* __restrict__ W1, const float* __restrict__ b1,
    const float* __restrict__ W2, const float* __restrict__ b2,
    uint* __restrict__ sxp)
{
  extern __shared__ char smraw[];
  ushort* h1b = (ushort*)smraw;            // [208][72] bf16 (row 207 = zero pad)
  float*  xs6 = (float*)(h1b + 208*HW);    // [207][36] (stride 36: 2-way banks, exact 9xfloat4)
  float*  W1s = xs6 + 207*XS6;             // [6][64]
  float*  b1s = W1s + NF*64;
  float*  b2s = b1s + 64;
  float*  S2_ = b2s + 64;                  // [6][64]
  float*  r1_ = S2_ + 6*64;                // [6][64]
  float*  xsA = r1_ + 6*64;                // [6][8]

  const int tid = threadIdx.x;
  const int tg = blockIdx.x, b = blockIdx.y;
  const float inv = 1.0f/208.0f;
  const int l = tid & 63;
  const int w = __builtin_amdgcn_readfirstlane(tid >> 6);
  const int col = l & 15, q = l >> 4;
  const int cw = w*16 + col;

  for (int i=tid; i<6*64; i+=256){ S2_[i]=0.f; r1_[i]=0.f; }
  if (tid < 48) xsA[tid] = 0.f;
  if (tid < 72) h1b[207*HW + tid] = 0;

  for (int i=tid;i<NF*64;i+=256) W1s[i]=W1[i];
  if (tid<64){ b1s[tid]=b1[tid]; b2s[tid]=b2[tid]; }
  {
    const float* xb = x + (size_t)b*NN*(NT*NF) + (size_t)tg*36;
    for (int i=tid; i<207*9; i+=256){
      int n = i/9, c = (i - n*9)*4;
      *(float4*)&xs6[n*XS6 + c] = *(const float4*)&xb[(size_t)n*(NT*NF) + c];
    }
  }
  __syncthreads();

  if (tid < 144){
    int tt = tid/24, rem = tid - tt*24, f = rem>>2, p = rem&3;
    float ps = 0.f;
    for (int n=p; n<NN; n+=4) ps += xs6[n*XS6 + tt*6 + f];
    atomicAdd(&xsA[tt*8+f], ps);
  }

  float wtmp[16];
  #pragma unroll
  for (int kc=0;kc<2;kc++)
    #pragma unroll
    for (int j=0;j<8;j++)
      wtmp[kc*8+j] = W2[(size_t)(kc*32 + q*8 + j)*64 + cw];
  bf8_t B2[2];
  #pragma unroll
  for (int kc=0;kc<2;kc++){
    bf8_t ph;
    #pragma unroll
    for (int j=0;j<8;j++) ph[j] = (short)bf16h(wtmp[kc*8+j]);
    B2[kc]=ph;
  }

  // S2 W2-slice cached in regs (tt-invariant): thread (pp2,h2) covers k=pp2*16..+16
  const int h2i = tid & 63, pp2 = tid >> 6;
  float w2c[16];
  #pragma unroll
  for (int k=0;k<16;k++) w2c[k] = W2[(size_t)(pp2*16+k)*64 + h2i];

  __syncthreads();

  const int ht4 = (tid & 15) * 4;
  const int nti = tid >> 4;

  #pragma unroll 1
  for (int tt=0; tt<6; tt++){
    const int t = tg*6 + tt;
    // ---- layer 1: h1 = relu((x@W1 + S1)/208 + b1) -> bf16 plane + r1 ----
    {
      float s1v[4];
      #pragma unroll
      for (int j=0;j<4;j++){
        float a = 0.f;
        #pragma unroll
        for (int f=0;f<NF;f++) a += xsA[tt*8+f]*W1s[f*64 + ht4 + j];
        s1v[j] = a;
      }
      float cs0=0.f, cs1=0.f, cs2=0.f, cs3=0.f;
      #pragma unroll
      for (int p=0;p<4;p++){
        int nt = p*16 + nti;
        if (nt < 52){
          #pragma unroll
          for (int i=0;i<4;i++){
            int n = 4*nt+i;
            if (n < NN){
              float a0=0.f,a1=0.f,a2=0.f,a3=0.f;
              #pragma unroll
              for (int f=0;f<NF;f++){
                float xv = xs6[n*XS6 + tt*6 + f];
                float4 wv = *(const float4*)&W1s[f*64 + ht4];
                a0+=xv*wv.x; a1+=xv*wv.y; a2+=xv*wv.z; a3+=xv*wv.w;
              }
              float v0=(a0+s1v[0])*inv + b1s[ht4+0]; v0 = v0>0.f?v0:0.f;
              float v1=(a1+s1v[1])*inv + b1s[ht4+1]; v1 = v1>0.f?v1:0.f;
              float v2=(a2+s1v[2])*inv + b1s[ht4+2]; v2 = v2>0.f?v2:0.f;
              float v3=(a3+s1v[3])*inv + b1s[ht4+3]; v3 = v3>0.f?v3:0.f;
              ushort4 hi;
              hi.x=bf16h(v0); hi.y=bf16h(v1); hi.z=bf16h(v2); hi.w=bf16h(v3);
              *(ushort4*)&h1b[n*HW + ht4] = hi;
              cs0+=v0; cs1+=v1; cs2+=v2; cs3+=v3;
            }
          }
        }
      }
      atomicAdd(&r1_[tt*64+ht4+0], cs0);
      atomicAdd(&r1_[tt*64+ht4+1], cs1);
      atomicAdd(&r1_[tt*64+ht4+2], cs2);
      atomicAdd(&r1_[tt*64+ht4+3], cs3);
    }
    lds_barrier();   // h1b writes + r1 atomics visible; prior-tt stores NOT drained

    // ---- S2 = r1 @ W2 (fp32 exact, W2 slice from regs) ----
    {
      float ps = 0.f;
      #pragma unroll
      for (int k=0;k<16;k++) ps += r1_[tt*64+pp2*16+k]*w2c[k];
      atomicAdd(&S2_[tt*64+h2i], ps);
    }

    // ---- layer 2: single-bf16 MFMA ----
    f4_t acc[13];
    #pragma unroll
    for (int mt=0;mt<13;mt++){ f4_t z; z[0]=0.f;z[1]=0.f;z[2]=0.f;z[3]=0.f; acc[mt]=z; }
    #pragma unroll 2
    for (int mt=0;mt<13;mt++){
      #pragma unroll
      for (int kc=0;kc<2;kc++){
        bf8_t ah = *(const bf8_t*)(h1b + (mt*16+col)*HW + kc*32 + q*8);
        acc[mt] = __builtin_amdgcn_mfma_f32_16x16x32_bf16(ah, B2[kc], acc[mt], 0,0,0);
      }
    }
    lds_barrier();   // S2 atomics + all h1 reads complete (h1b free for tt+1)

    // ---- epilogue: h2 split-bf16 -> packed dword at [t][b*207+n][cw] ----
    {
      const float s2v = S2_[tt*64+cw], b2v = b2s[cw];
      const size_t obase = (size_t)t*TSU + (size_t)(b*NN)*NH + cw;
      #pragma unroll
      for (int mt=0;mt<13;mt++){
        #pragma unroll
        for (int r=0;r<4;r++){
          int n = mt*16 + q*4 + r;
          if (n < NN){
            float v = (acc[mt][r] + s2v)*inv + b2v;
            v = v>0.f ? v : 0.f;
            ushort hb = bf16h(v);
            ushort lb = bf16h(v - bf16f(hb));
            sxp[obase + (size_t)n*NH] = ((uint)hb << 16) | (uint)lb;
          }
        }
      }
    }
  }
}

// ---------------- LSTM v21 (best measured: 166 us) — unchanged ----------------
#define HS2 72   // ushort stride per h row

__global__ __launch_bounds__(256, 2) void lstm21_kernel(
    const uint* __restrict__ sxp,
    const float* __restrict__ Wih, const float* __restrict__ Whh,
    const float* __restrict__ bih, const float* __restrict__ bhh,
    const float* __restrict__ Wfc, const float* __restrict__ bfc, float* __restrict__ out)
{
  __shared__ __align__(16) ushort hhp[2][2][16*HS2 + 8];   // [buf][set] hi plane (9.3 KB)
  __shared__ __align__(16) ushort hlp[2][2][16*HS2 + 8];   // [buf][set] lo plane (9.3 KB)
  __shared__ __align__(16) ushort xst[2][2][2][2][512];    // [par][set][plane][kk][512] (16 KB)

  const int tid = threadIdx.x;
  const int l = tid & 63;
  const int w = __builtin_amdgcn_readfirstlane(tid >> 6);
  const int col = l & 15, q = l >> 4;
  const int g = blockIdx.x;

  // B fragments: [ty][mat*2+kk]; mat 0 = Wih (x), 1 = Whh (h). 128 VGPRs.
  bf8_t Bh[4][4], Bl[4][4];
  #pragma unroll
  for (int mat=0; mat<2; mat++){
    const float* W = mat ? Whh : Wih;
    #pragma unroll
    for (int ty=0; ty<4; ty++){
      #pragma unroll
      for (int kk=0; kk<2; kk++){
        const float* wp = W + (size_t)(ty*64 + w*16 + col)*64 + kk*32 + q*8;
        bf8_t ph, pl2;
        #pragma unroll
        for (int j=0;j<8;j++){
          float wv = wp[j];
          ushort hb = bf16h(wv);
          ph[j] = (short)hb;
          pl2[j] = (short)bf16h(wv - bf16f(hb));
        }
        Bh[ty][mat*2+kk] = ph;
        Bl[ty][mat*2+kk] = pl2;
      }
    }
  }
  float bias[4];
  #pragma unroll
  for (int ty=0;ty<4;ty++){
    int r = ty*64 + w*16 + col;
    bias[ty] = bih[r] + bhh[r];
  }
  float c[2][4];
  #pragma unroll
  for (int s=0;s<2;s++)
    #pragma unroll
    for (int i=0;i<4;i++) c[s][i]=0.f;

  for (int i=tid; i<16*HS2; i+=256){
    hhp[0][0][i]=0; hhp[0][1][i]=0; hlp[0][0][i]=0; hlp[0][1][i]=0;
  }

  // stage role: wave w owns (set ss, k-half hf); lane loads 8 packed dwords
  // = h-dims hf*32+q*8 .. +8 of seq (g*32 + ss*16 + col).
  const int ss = w >> 1, hf = w & 1;
  const uint* xsrc = sxp + (size_t)(g*32 + ss*16 + col)*64 + (size_t)(hf*32 + q*8);

  // de-interleave 8 packed dwords -> hi uint4 + lo uint4 (2 ushorts each)
  #define DEINT(A8, B8, HU, LU) do { \
    uint _d[8] = {(A8).x,(A8).y,(A8).z,(A8).w,(B8).x,(B8).y,(B8).z,(B8).w}; \
    (HU).x = (_d[1] & 0xffff0000u) | (_d[0] >> 16); \
    (HU).y = (_d[3] & 0xffff0000u) | (_d[2] >> 16); \
    (HU).z = (_d[5] & 0xffff0000u) | (_d[4] >> 16); \
    (HU).w = (_d[7] & 0xffff0000u) | (_d[6] >> 16); \
    (LU).x = (_d[1] << 16) | (_d[0] & 0xffffu); \
    (LU).y = (_d[3] << 16) | (_d[2] & 0xffffu); \
    (LU).z = (_d[5] << 16) | (_d[4] & 0xffffu); \
    (LU).w = (_d[7] << 16) | (_d[6] & 0xffffu); \
  } while(0)

  // prologue: stage t=0 -> xst[0], t=1 -> xst[1]
  #pragma unroll
  for (int t2=0; t2<2; t2++){
    uint4 a8 = *(const uint4*)(xsrc + (size_t)t2*TSU);
    uint4 b8 = *(const uint4*)(xsrc + (size_t)t2*TSU + 4);
    uint4 hu, lu;
    DEINT(a8, b8, hu, lu);
    *(uint4*)&xst[t2][ss][0][hf][l*8] = hu;
    *(uint4*)&xst[t2][ss][1][hf][l*8] = lu;
  }

  const int d = w*16 + col;
  __syncthreads();

  #pragma unroll 2
  for (int t=0; t<NT; t++){
    const int cur = t & 1;

    // ---- stage issue for t+2 (regs; LDS-written post-barrier) ----
    uint4 ga, gb;
    const bool do_stage = (t+2 < NT);
    if (do_stage){
      ga = *(const uint4*)(xsrc + (size_t)(t+2)*TSU);
      gb = *(const uint4*)(xsrc + (size_t)(t+2)*TSU + 4);
    }

    // ---- x-phase: lane-linear frag reads (conflict-free), 48 MFMAs ----
    bf8_t xh0[2], xh1[2], xl0[2], xl1[2];
    #pragma unroll
    for (int s=0;s<2;s++){
      xh0[s] = *(const bf8_t*)&xst[cur][s][0][0][l*8];
      xh1[s] = *(const bf8_t*)&xst[cur][s][0][1][l*8];
      xl0[s] = *(const bf8_t*)&xst[cur][s][1][0][l*8];
      xl1[s] = *(const bf8_t*)&xst[cur][s][1][1][l*8];
    }

    f4_t acc[2][4];
    #pragma unroll
    for (int s=0;s<2;s++)
      #pragma unroll
      for (int ty=0;ty<4;ty++){ f4_t z; z[0]=bias[ty];z[1]=bias[ty];z[2]=bias[ty];z[3]=bias[ty]; acc[s][ty]=z; }
    #pragma unroll
    for (int s=0;s<2;s++)
      #pragma unroll
      for (int ty=0;ty<4;ty++){
        acc[s][ty] = __builtin_amdgcn_mfma_f32_16x16x32_bf16(xh0[s], Bh[ty][0], acc[s][ty], 0,0,0);
        acc[s][ty] = __builtin_amdgcn_mfma_f32_16x16x32_bf16(xl0[s], Bh[ty][0], acc[s][ty], 0,0,0);
        acc[s][ty] = __builtin_amdgcn_mfma_f32_16x16x32_bf16(xh0[s], Bl[ty][0], acc[s][ty], 0,0,0);
        acc[s][ty] = __builtin_amdgcn_mfma_f32_16x16x32_bf16(xh1[s], Bh[ty][1], acc[s][ty], 0,0,0);
        acc[s][ty] = __builtin_amdgcn_mfma_f32_16x16x32_bf16(xl1[s], Bh[ty][1], acc[s][ty], 0,0,0);
        acc[s][ty] = __builtin_amdgcn_mfma_f32_16x16x32_bf16(xh1[s], Bl[ty][1], acc[s][ty], 0,0,0);
      }

    lds_barrier();   // h(t-1) + xst[cur] reads drained; x prefetch NOT drained

    // ---- h-phase: ds_read_b128 straight into A-frags, 48 MFMAs ----
    bf8_t hh0[2], hh1[2], hl0[2], hl1[2];
    #pragma unroll
    for (int s=0;s<2;s++){
      const ushort* ph = &hhp[cur][s][0] + col*HS2 + q*8;
      const ushort* pl2 = &hlp[cur][s][0] + col*HS2 + q*8;
      hh0[s] = *(const bf8_t*)(ph);
      hh1[s] = *(const bf8_t*)(ph + 32);
      hl0[s] = *(const bf8_t*)(pl2);
      hl1[s] = *(const bf8_t*)(pl2 + 32);
    }
    #pragma unroll
    for (int s=0;s<2;s++)
      #pragma unroll
      for (int ty=0;ty<4;ty++){
        acc[s][ty] = __builtin_amdgcn_mfma_f32_16x16x32_bf16(hh0[s], Bh[ty][2], acc[s][ty], 0,0,0);
        acc[s][ty] = __builtin_amdgcn_mfma_f32_16x16x32_bf16(hl0[s], Bh[ty][2], acc[s][ty], 0,0,0);
        acc[s][ty] = __builtin_amdgcn_mfma_f32_16x16x32_bf16(hh0[s], Bl[ty][2], acc[s][ty], 0,0,0);
        acc[s][ty] = __builtin_amdgcn_mfma_f32_16x16x32_bf16(hh1[s], Bh[ty][3], acc[s][ty], 0,0,0);
        acc[s][ty] = __builtin_amdgcn_mfma_f32_16x16x32_bf16(hl1[s], Bh[ty][3], acc[s][ty], 0,0,0);
        acc[s][ty] = __builtin_amdgcn_mfma_f32_16x16x32_bf16(hh1[s], Bl[ty][3], acc[s][ty], 0,0,0);
      }

    // ---- stage write (t+2) into xst[cur]: post-barrier, so all waves'
    //      reads of this buffer are drained; next barrier publishes it ----
    if (do_stage){
      uint4 hu, lu;
      DEINT(ga, gb, hu, lu);
      *(uint4*)&xst[cur][ss][0][hf][l*8] = hu;
      *(uint4*)&xst[cur][ss][1][hf][l*8] = lu;
    }

    // ---- epilogue both sets: gates -> c,h; cvt_pk split-pack ----
    #pragma unroll
    for (int s=0;s<2;s++){
      ushort* wh = &hhp[cur^1][s][0];
      ushort* wl = &hlp[cur^1][s][0];
      float hv[4];
      #pragma unroll
      for (int r=0;r<4;r++){
        float ig = fsig(acc[s][0][r]);
        float fg = fsig(acc[s][1][r]);
        float gt = ftanh(acc[s][2][r]);
        float og = fsig(acc[s][3][r]);
        float cc = fg*c[s][r] + ig*gt;
        c[s][r] = cc;
        hv[r] = og*ftanh(cc);
      }
      const int o0 = (q*4)*HS2 + d;
      if (t != NT-1){
        uint ph01, ph23, pl01, pl23;
        asm("v_cvt_pk_bf16_f32 %0, %1, %2" : "=v"(ph01) : "v"(hv[0]), "v"(hv[1]));
        asm("v_cvt_pk_bf16_f32 %0, %1, %2" : "=v"(ph23) : "v"(hv[2]), "v"(hv[3]));
        float r0 = hv[0] - __uint_as_float(ph01 << 16);
        float r1 = hv[1] - __uint_as_float(ph01 & 0xffff0000u);
        float r2 = hv[2] - __uint_as_float(ph23 << 16);
        float r3 = hv[3] - __uint_as_float(ph23 & 0xffff0000u);
        asm("v_cvt_pk_bf16_f32 %0, %1, %2" : "=v"(pl01) : "v"(r0), "v"(r1));
        asm("v_cvt_pk_bf16_f32 %0, %1, %2" : "=v"(pl23) : "v"(r2), "v"(r3));
        wh[o0]         = (ushort)ph01;
        wh[o0 + HS2]   = (ushort)(ph01 >> 16);
        wh[o0 + 2*HS2] = (ushort)ph23;
        wh[o0 + 3*HS2] = (ushort)(ph23 >> 16);
        wl[o0]         = (ushort)pl01;
        wl[o0 + HS2]   = (ushort)(pl01 >> 16);
        wl[o0 + 2*HS2] = (ushort)pl23;
        wl[o0 + 3*HS2] = (ushort)(pl23 >> 16);
      } else {
        #pragma unroll
        for (int r=0;r<4;r++){
          uint bits = __float_as_uint(hv[r]);
          wh[o0 + r*HS2] = (ushort)(bits >> 16);
          wl[o0 + r*HS2] = (ushort)(bits & 0xffffu);
        }
      }
    }
  }
  __syncthreads();   // final h (f32 bits split across planes) visible to FC lanes

  if (tid < 32){
    const int s = tid >> 4, r = tid & 15;
    float a = bfc[0];
    const ushort* fh = &hhp[NT&1][s][0] + r*HS2;
    const ushort* fl = &hlp[NT&1][s][0] + r*HS2;
    #pragma unroll 8
    for (int k=0;k<64;k++){
      float v = __uint_as_float(((uint)fh[k] << 16) | (uint)fl[k]);
      a += v * Wfc[k];
    }
    out[g*32 + tid] = a;
  }
}

extern "C" void kernel_launch(void* const* d_in, const int* in_sizes, int n_in,
                              void* d_out, int out_size, void* d_ws, size_t ws_size,
                              hipStream_t stream) {
  const float* x   = (const float*)d_in[0];
  // d_in[1], d_in[2] (N1, N2): structurally dead — sigmoid(N1@N2)>0 is all-ones.
  const float* W1  = (const float*)d_in[3];
  const float* b1  = (const float*)d_in[4];
  const float* W2  = (const float*)d_in[5];
  const float* b2  = (const float*)d_in[6];
  const float* Wih = (const float*)d_in[7];
  const float* Whh = (const float*)d_in[8];
  const float* bih = (const float*)d_in[9];
  const float* bhh = (const float*)d_in[10];
  const float* Wfc = (const float*)d_in[11];
  const float* bfc = (const float*)d_in[12];

  uint* sxp = (uint*)d_ws;                     // [48][13248][64] packed (hi<<16|lo), 162.8 MB
  float* out = (float*)d_out;

  hipFuncSetAttribute((const void*)gcn_kernel, hipFuncAttributeMaxDynamicSharedMemorySize, GCN7_LDS_BYTES);

  gcn_kernel<<<dim3(NT/6, NB), 256, GCN7_LDS_BYTES, stream>>>(x, W1, b1, W2, b2, sxp);
  lstm21_kernel<<<NG2, 256, 0, stream>>>(sxp, Wih, Whh, bih, bhh, Wfc, bfc, out);
}